// Round 1
// baseline (554.205 us; speedup 1.0000x reference)
//
#include <hip/hip_runtime.h>

constexpr int BB = 128, TT = 1000, IN = 3, OUT = 3, HID = 512, RR = 2;
constexpr float NSTD = 0.05f, TAU = 0.2f;

#define DEVINL __device__ __forceinline__

// exact identity tanh(x) = 1 - 2/(exp(2x)+1); __expf -> v_exp_f32, rcp -> v_rcp_f32
DEVINL float fast_tanh(float x) {
    float e = __expf(2.0f * x);
    return 1.0f - 2.0f * __builtin_amdgcn_rcpf(e + 1.0f);
}

// Full-wave (64-lane) sum via DPP: result valid in lane 63.
// row_shr 1/2/4/8 (bound_ctrl), then row_bcast15 (rows 1,3), row_bcast31 (rows 2,3).
DEVINL float dpp_sum64(float v) {
    int t;
    t = __builtin_amdgcn_update_dpp(0, __builtin_bit_cast(int, v), 0x111, 0xF, 0xF, true);
    v += __builtin_bit_cast(float, t);
    t = __builtin_amdgcn_update_dpp(0, __builtin_bit_cast(int, v), 0x112, 0xF, 0xF, true);
    v += __builtin_bit_cast(float, t);
    t = __builtin_amdgcn_update_dpp(0, __builtin_bit_cast(int, v), 0x114, 0xF, 0xF, true);
    v += __builtin_bit_cast(float, t);
    t = __builtin_amdgcn_update_dpp(0, __builtin_bit_cast(int, v), 0x118, 0xF, 0xF, true);
    v += __builtin_bit_cast(float, t);
    t = __builtin_amdgcn_update_dpp(0, __builtin_bit_cast(int, v), 0x142, 0xA, 0xF, true);
    v += __builtin_bit_cast(float, t);
    t = __builtin_amdgcn_update_dpp(0, __builtin_bit_cast(int, v), 0x143, 0xC, 0xF, true);
    v += __builtin_bit_cast(float, t);
    return v;
}

// Kernel A: sequential scan. One block per batch element, 256 threads, 2 hidden/thread.
__global__ __launch_bounds__(256, 1) void rnn_scan_kernel(
    const float* __restrict__ u,      // [B,T,IN]
    const float* __restrict__ x0,     // [B,HID]
    const float* __restrict__ noise,  // [T,B,HID]
    const float* __restrict__ M,      // [HID,R]
    const float* __restrict__ Nw,     // [HID,R]
    const float* __restrict__ bias,   // [HID]
    const float* __restrict__ Win,    // [HID,IN]
    float* __restrict__ out_xf,       // [B,HID]
    float* __restrict__ traj)         // [B,T+1,HID]
{
    const int b    = blockIdx.x;
    const int tid  = threadIdx.x;      // 0..255
    const int wave = tid >> 6;         // 0..3
    const int lane = tid & 63;
    const int h0   = tid * 2;          // this thread's hidden units: h0, h0+1

    __shared__ __align__(16) float kpart[2][4][2];  // [parity][wave][q]

    // per-thread weights (vectorized: h0*RR is 16B-aligned)
    const float4 nv = *reinterpret_cast<const float4*>(Nw + h0 * RR); // N[h0][0..1], N[h0+1][0..1]
    const float4 mv = *reinterpret_cast<const float4*>(M  + h0 * RR);
    const float2 bv = *reinterpret_cast<const float2*>(bias + h0);
    const float w00 = Win[h0*IN+0], w01 = Win[h0*IN+1], w02 = Win[h0*IN+2];
    const float w10 = Win[h0*IN+3], w11 = Win[h0*IN+4], w12 = Win[h0*IN+5];

    float2 x = *reinterpret_cast<const float2*>(x0 + (size_t)b * HID + h0);
    // trajectories[:,0,:] = x0 (exact copy)
    *reinterpret_cast<float2*>(traj + (size_t)b * (TT + 1) * HID + h0) = x;

    // r0 = tanh(x0)  (NO bias, matches reference)
    float r0 = fast_tanh(x.x), r1 = fast_tanh(x.y);

    const float* nzbase = noise + (size_t)b * HID + h0;
    float2 nz0 = *reinterpret_cast<const float2*>(nzbase + (size_t)0 * BB * HID);
    float2 nz1 = *reinterpret_cast<const float2*>(nzbase + (size_t)1 * BB * HID);
    float2 nz2 = *reinterpret_cast<const float2*>(nzbase + (size_t)2 * BB * HID);
    float2 nz3 = *reinterpret_cast<const float2*>(nzbase + (size_t)3 * BB * HID);

    const float* ub = u + (size_t)b * TT * IN;
    float* trj = traj + (size_t)b * (TT + 1) * HID + HID + h0;  // row t=1

    // pre-loop kappa(r0) -> parity 0
    {
        float p0 = fmaf(r0, nv.x, r1 * nv.z);
        float p1 = fmaf(r0, nv.y, r1 * nv.w);
        p0 = dpp_sum64(p0);
        p1 = dpp_sum64(p1);
        if (lane == 63) { kpart[0][wave][0] = p0; kpart[0][wave][1] = p1; }
    }

    for (int t = 0; t < TT; ++t) {
        const int p = t & 1;
        // prefetch noise 4 steps ahead (issue before barrier)
        const int tp = (t + 4 < TT) ? (t + 4) : (TT - 1);
        float2 nzn = *reinterpret_cast<const float2*>(nzbase + (size_t)tp * BB * HID);
        // u_t (block-uniform scalar loads)
        const float uu0 = ub[t*IN+0], uu1 = ub[t*IN+1], uu2 = ub[t*IN+2];

        __syncthreads();  // kappa partials of step t visible

        float4 ka = *reinterpret_cast<const float4*>(&kpart[p][0][0]);  // waves 0,1
        float4 kb = *reinterpret_cast<const float4*>(&kpart[p][2][0]);  // waves 2,3
        const float k0 = (ka.x + ka.z) + (kb.x + kb.z);
        const float k1 = (ka.y + ka.w) + (kb.y + kb.w);

        const float It0 = fmaf(uu0, w00, fmaf(uu1, w01, uu2 * w02));
        const float It1 = fmaf(uu0, w10, fmaf(uu1, w11, uu2 * w12));
        const float hw0 = fmaf(k0, mv.x, k1 * mv.y) * (1.0f / HID);
        const float hw1 = fmaf(k0, mv.z, k1 * mv.w) * (1.0f / HID);

        // x_new = (1-tau)*x + nstd*n + tau*(hw + I)
        const float xn0 = fmaf(1.0f - TAU, x.x, fmaf(NSTD, nz0.x, TAU * (hw0 + It0)));
        const float xn1 = fmaf(1.0f - TAU, x.y, fmaf(NSTD, nz0.y, TAU * (hw1 + It1)));
        float2 xn; xn.x = xn0; xn.y = xn1;
        *reinterpret_cast<float2*>(trj + (size_t)t * HID) = xn;

        // r_new = tanh(x_new + bias); reduce next kappa
        const float rr0 = fast_tanh(xn0 + bv.x);
        const float rr1 = fast_tanh(xn1 + bv.y);
        float q0 = fmaf(rr0, nv.x, rr1 * nv.z);
        float q1 = fmaf(rr0, nv.y, rr1 * nv.w);
        q0 = dpp_sum64(q0);
        q1 = dpp_sum64(q1);
        if (lane == 63) { kpart[p ^ 1][wave][0] = q0; kpart[p ^ 1][wave][1] = q1; }

        x = xn;
        nz0 = nz1; nz1 = nz2; nz2 = nz3; nz3 = nzn;
    }

    *reinterpret_cast<float2*>(out_xf + (size_t)b * HID + h0) = x;
}

// Kernel B: output projection y[b,t,o] = sum_h tanh(traj[b,t+1,h]) * Wout[o,h]
// wave-per-row, grid-stride. Memory-bound (reads 256 MB).
__global__ __launch_bounds__(256, 4) void proj_kernel(
    const float* __restrict__ traj,   // [B,T+1,HID]
    const float* __restrict__ Wout,   // [OUT,HID]
    float* __restrict__ y)            // [B,T,OUT]
{
    const int lane = threadIdx.x & 63;
    const int gw   = (int)((blockIdx.x * blockDim.x + threadIdx.x) >> 6);
    const int nw   = (int)((gridDim.x * blockDim.x) >> 6);

    // each lane covers 8 consecutive h: preload Wout slices once
    const float4 wa0 = *reinterpret_cast<const float4*>(Wout + 0 * HID + lane * 8);
    const float4 wa1 = *reinterpret_cast<const float4*>(Wout + 0 * HID + lane * 8 + 4);
    const float4 wb0 = *reinterpret_cast<const float4*>(Wout + 1 * HID + lane * 8);
    const float4 wb1 = *reinterpret_cast<const float4*>(Wout + 1 * HID + lane * 8 + 4);
    const float4 wc0 = *reinterpret_cast<const float4*>(Wout + 2 * HID + lane * 8);
    const float4 wc1 = *reinterpret_cast<const float4*>(Wout + 2 * HID + lane * 8 + 4);

    for (int row = gw; row < BB * TT; row += nw) {
        const int b = row / TT;
        const int t = row - b * TT;
        const float* src = traj + ((size_t)b * (TT + 1) + (t + 1)) * HID + lane * 8;
        const float4 a = *reinterpret_cast<const float4*>(src);
        const float4 c = *reinterpret_cast<const float4*>(src + 4);

        const float t0 = fast_tanh(a.x), t1 = fast_tanh(a.y);
        const float t2 = fast_tanh(a.z), t3 = fast_tanh(a.w);
        const float t4 = fast_tanh(c.x), t5 = fast_tanh(c.y);
        const float t6 = fast_tanh(c.z), t7 = fast_tanh(c.w);

        float y0 = t0*wa0.x + t1*wa0.y + t2*wa0.z + t3*wa0.w
                 + t4*wa1.x + t5*wa1.y + t6*wa1.z + t7*wa1.w;
        float y1 = t0*wb0.x + t1*wb0.y + t2*wb0.z + t3*wb0.w
                 + t4*wb1.x + t5*wb1.y + t6*wb1.z + t7*wb1.w;
        float y2 = t0*wc0.x + t1*wc0.y + t2*wc0.z + t3*wc0.w
                 + t4*wc1.x + t5*wc1.y + t6*wc1.z + t7*wc1.w;

        y0 = dpp_sum64(y0);
        y1 = dpp_sum64(y1);
        y2 = dpp_sum64(y2);

        if (lane == 63) {
            float* dst = y + (size_t)row * OUT;
            dst[0] = y0; dst[1] = y1; dst[2] = y2;
        }
    }
}

extern "C" void kernel_launch(void* const* d_in, const int* in_sizes, int n_in,
                              void* d_out, int out_size, void* d_ws, size_t ws_size,
                              hipStream_t stream) {
    const float* u     = (const float*)d_in[0];
    const float* x0    = (const float*)d_in[1];
    const float* noise = (const float*)d_in[2];
    const float* M     = (const float*)d_in[3];
    const float* Nw    = (const float*)d_in[4];
    const float* bias  = (const float*)d_in[5];
    const float* Win   = (const float*)d_in[6];
    const float* Wout  = (const float*)d_in[7];

    float* out_y  = (float*)d_out;                        // [B,T,OUT]
    float* out_xf = out_y + (size_t)BB * TT * OUT;        // [B,HID]
    float* traj   = out_xf + (size_t)BB * HID;            // [B,T+1,HID]

    rnn_scan_kernel<<<BB, 256, 0, stream>>>(u, x0, noise, M, Nw, bias, Win, out_xf, traj);
    proj_kernel<<<2048, 256, 0, stream>>>(traj, Wout, out_y);
}

// Round 3
// 317.654 us; speedup vs baseline: 1.7447x; 1.7447x over previous
//
#include <hip/hip_runtime.h>

constexpr int BB = 128, TT = 1000, IN = 3, OUT = 3, HID = 512, RR = 2;
constexpr float NSTD = 0.05f, TAU = 0.2f;
constexpr float CEXP = 2.8853900817779268f;  // 2*log2(e)

#define DEVINL __device__ __forceinline__

// tanh(y) where arg = CEXP*y  (tanh = 1 - 2/(exp2(2*log2e*y)+1))
DEVINL float tanh_from_arg(float arg) {
    float e = __builtin_amdgcn_exp2f(arg);
    return fmaf(-2.0f, __builtin_amdgcn_rcpf(e + 1.0f), 1.0f);
}

DEVINL float fast_tanh(float x) {  // for proj kernel
    return tanh_from_arg(CEXP * x);
}

// Full-wave (64-lane) sum via DPP: result valid in lane 63.
DEVINL float dpp_sum64(float v) {
    int t;
    t = __builtin_amdgcn_update_dpp(0, __builtin_bit_cast(int, v), 0x111, 0xF, 0xF, true);
    v += __builtin_bit_cast(float, t);
    t = __builtin_amdgcn_update_dpp(0, __builtin_bit_cast(int, v), 0x112, 0xF, 0xF, true);
    v += __builtin_bit_cast(float, t);
    t = __builtin_amdgcn_update_dpp(0, __builtin_bit_cast(int, v), 0x114, 0xF, 0xF, true);
    v += __builtin_bit_cast(float, t);
    t = __builtin_amdgcn_update_dpp(0, __builtin_bit_cast(int, v), 0x118, 0xF, 0xF, true);
    v += __builtin_bit_cast(float, t);
    t = __builtin_amdgcn_update_dpp(0, __builtin_bit_cast(int, v), 0x142, 0xA, 0xF, true);
    v += __builtin_bit_cast(float, t);
    t = __builtin_amdgcn_update_dpp(0, __builtin_bit_cast(int, v), 0x143, 0xC, 0xF, true);
    v += __builtin_bit_cast(float, t);
    return v;
}

DEVINL float dot44(float4 ra, float4 na, float4 rb, float4 nb) {
    float s0 = fmaf(ra.y, na.y, ra.x * na.x);
    float s1 = fmaf(ra.w, na.w, ra.z * na.z);
    float s2 = fmaf(rb.y, nb.y, rb.x * nb.x);
    float s3 = fmaf(rb.w, nb.w, rb.z * nb.z);
    return (s0 + s1) + (s2 + s3);
}

// Kernel A: sequential scan. ONE WAVE per batch element. 8 hidden/lane
// (two contiguous float4 halves for coalescing). No LDS, no barriers:
// cross-lane reduce via DPP + readlane into SGPRs.
__global__ __launch_bounds__(64, 1) void rnn_scan_kernel(
    const float* __restrict__ u,      // [B,T,IN]
    const float* __restrict__ x0,     // [B,HID]
    const float* __restrict__ noise,  // [T,B,HID]
    const float* __restrict__ M,      // [HID,R]
    const float* __restrict__ Nw,     // [HID,R]
    const float* __restrict__ bias,   // [HID]
    const float* __restrict__ Win,    // [HID,IN]
    float* __restrict__ out_xf,       // [B,HID]
    float* __restrict__ traj)         // [B,T+1,HID]
{
    const int b    = blockIdx.x;
    const int lane = threadIdx.x;         // 0..63
    const int hA   = lane * 4;            // h in [hA, hA+3]
    const int hB   = 256 + lane * 4;      // h in [hB, hB+3]

    // ---- per-lane constants ----
    float4 ta, tb_;
    ta  = *reinterpret_cast<const float4*>(Nw + 2 * hA);
    tb_ = *reinterpret_cast<const float4*>(Nw + 2 * hA + 4);
    const float4 nc0A = make_float4(ta.x, ta.z, tb_.x, tb_.z);
    const float4 nc1A = make_float4(ta.y, ta.w, tb_.y, tb_.w);
    ta  = *reinterpret_cast<const float4*>(Nw + 2 * hB);
    tb_ = *reinterpret_cast<const float4*>(Nw + 2 * hB + 4);
    const float4 nc0B = make_float4(ta.x, ta.z, tb_.x, tb_.z);
    const float4 nc1B = make_float4(ta.y, ta.w, tb_.y, tb_.w);

    const float MS = TAU / (float)HID;    // fold tau/hid into M
    ta  = *reinterpret_cast<const float4*>(M + 2 * hA);
    tb_ = *reinterpret_cast<const float4*>(M + 2 * hA + 4);
    const float4 mc0A = make_float4(ta.x * MS, ta.z * MS, tb_.x * MS, tb_.z * MS);
    const float4 mc1A = make_float4(ta.y * MS, ta.w * MS, tb_.y * MS, tb_.w * MS);
    ta  = *reinterpret_cast<const float4*>(M + 2 * hB);
    tb_ = *reinterpret_cast<const float4*>(M + 2 * hB + 4);
    const float4 mc0B = make_float4(ta.x * MS, ta.z * MS, tb_.x * MS, tb_.z * MS);
    const float4 mc1B = make_float4(ta.y * MS, ta.w * MS, tb_.y * MS, tb_.w * MS);

    float4 bv = *reinterpret_cast<const float4*>(bias + hA);
    const float4 cbA = make_float4(CEXP * bv.x, CEXP * bv.y, CEXP * bv.z, CEXP * bv.w);
    bv = *reinterpret_cast<const float4*>(bias + hB);
    const float4 cbB = make_float4(CEXP * bv.x, CEXP * bv.y, CEXP * bv.z, CEXP * bv.w);

    float tw[2][4][3];  // TAU * Win rows (all indices compile-time in unrolled code)
    #pragma unroll
    for (int i = 0; i < 4; ++i) {
        #pragma unroll
        for (int k = 0; k < 3; ++k) {
            tw[0][i][k] = TAU * Win[(hA + i) * IN + k];
            tw[1][i][k] = TAU * Win[(hB + i) * IN + k];
        }
    }

    // ---- state ----
    float4 xA = *reinterpret_cast<const float4*>(x0 + (size_t)b * HID + hA);
    float4 xB = *reinterpret_cast<const float4*>(x0 + (size_t)b * HID + hB);

    float* trj = traj + (size_t)b * (TT + 1) * HID;
    *reinterpret_cast<float4*>(trj + hA) = xA;  // trajectories[:,0,:] = x0
    *reinterpret_cast<float4*>(trj + hB) = xB;
    trj += HID;  // now points at row t=1

    // r0 = tanh(x0) WITHOUT bias -> initial kappa
    float k0, k1;
    {
        float4 rA, rB;
        rA.x = tanh_from_arg(CEXP * xA.x); rA.y = tanh_from_arg(CEXP * xA.y);
        rA.z = tanh_from_arg(CEXP * xA.z); rA.w = tanh_from_arg(CEXP * xA.w);
        rB.x = tanh_from_arg(CEXP * xB.x); rB.y = tanh_from_arg(CEXP * xB.y);
        rB.z = tanh_from_arg(CEXP * xB.z); rB.w = tanh_from_arg(CEXP * xB.w);
        float p0 = dot44(rA, nc0A, rB, nc0B);
        float p1 = dot44(rA, nc1A, rB, nc1B);
        p0 = dpp_sum64(p0);
        p1 = dpp_sum64(p1);
        k0 = __builtin_bit_cast(float, __builtin_amdgcn_readlane(__builtin_bit_cast(int, p0), 63));
        k1 = __builtin_bit_cast(float, __builtin_amdgcn_readlane(__builtin_bit_cast(int, p1), 63));
    }

    // ---- register pipelines (depth 4, statically indexed via unroll-4) ----
    const float* nzA = noise + (size_t)b * HID + hA;
    const float* nzB = noise + (size_t)b * HID + hB;
    const float* ub  = u + (size_t)b * TT * IN;

    float4 nA[4], nB[4];
    float  up0[4], up1[4], up2[4];
    #pragma unroll
    for (int j = 0; j < 4; ++j) {
        nA[j]  = *reinterpret_cast<const float4*>(nzA + (size_t)j * (BB * HID));
        nB[j]  = *reinterpret_cast<const float4*>(nzB + (size_t)j * (BB * HID));
        up0[j] = ub[j * IN + 0];
        up1[j] = ub[j * IN + 1];
        up2[j] = ub[j * IN + 2];
    }

    for (int tb = 0; tb < TT; tb += 4) {
        #pragma unroll
        for (int j = 0; j < 4; ++j) {
            const int t = tb + j;
            // consume pipeline slot j
            const float uu0 = up0[j], uu1 = up1[j], uu2 = up2[j];
            const float4 nzAv = nA[j], nzBv = nB[j];

            // prefetch t+4 into slot j (clamped; redundant tail loads are harmless)
            int tp = t + 4; if (tp > TT - 1) tp = TT - 1;
            nA[j]  = *reinterpret_cast<const float4*>(nzA + (size_t)tp * (BB * HID));
            nB[j]  = *reinterpret_cast<const float4*>(nzB + (size_t)tp * (BB * HID));
            up0[j] = ub[tp * IN + 0];
            up1[j] = ub[tp * IN + 1];
            up2[j] = ub[tp * IN + 2];

            // c = 0.8*x + NSTD*n + TAU*(Win u)   (off critical path)
            float4 cA, cB;
            cA.x = fmaf(uu0, tw[0][0][0], fmaf(uu1, tw[0][0][1], uu2 * tw[0][0][2]));
            cA.y = fmaf(uu0, tw[0][1][0], fmaf(uu1, tw[0][1][1], uu2 * tw[0][1][2]));
            cA.z = fmaf(uu0, tw[0][2][0], fmaf(uu1, tw[0][2][1], uu2 * tw[0][2][2]));
            cA.w = fmaf(uu0, tw[0][3][0], fmaf(uu1, tw[0][3][1], uu2 * tw[0][3][2]));
            cB.x = fmaf(uu0, tw[1][0][0], fmaf(uu1, tw[1][0][1], uu2 * tw[1][0][2]));
            cB.y = fmaf(uu0, tw[1][1][0], fmaf(uu1, tw[1][1][1], uu2 * tw[1][1][2]));
            cB.z = fmaf(uu0, tw[1][2][0], fmaf(uu1, tw[1][2][1], uu2 * tw[1][2][2]));
            cB.w = fmaf(uu0, tw[1][3][0], fmaf(uu1, tw[1][3][1], uu2 * tw[1][3][2]));

            cA.x = fmaf(NSTD, nzAv.x, cA.x); cA.y = fmaf(NSTD, nzAv.y, cA.y);
            cA.z = fmaf(NSTD, nzAv.z, cA.z); cA.w = fmaf(NSTD, nzAv.w, cA.w);
            cB.x = fmaf(NSTD, nzBv.x, cB.x); cB.y = fmaf(NSTD, nzBv.y, cB.y);
            cB.z = fmaf(NSTD, nzBv.z, cB.z); cB.w = fmaf(NSTD, nzBv.w, cB.w);

            cA.x = fmaf(1.0f - TAU, xA.x, cA.x); cA.y = fmaf(1.0f - TAU, xA.y, cA.y);
            cA.z = fmaf(1.0f - TAU, xA.z, cA.z); cA.w = fmaf(1.0f - TAU, xA.w, cA.w);
            cB.x = fmaf(1.0f - TAU, xB.x, cB.x); cB.y = fmaf(1.0f - TAU, xB.y, cB.y);
            cB.z = fmaf(1.0f - TAU, xB.z, cB.z); cB.w = fmaf(1.0f - TAU, xB.w, cB.w);

            // x_new = c + k0*M'[:,0] + k1*M'[:,1]   (k0,k1 uniform SGPRs)
            float4 xnA, xnB;
            xnA.x = fmaf(mc0A.x, k0, fmaf(mc1A.x, k1, cA.x));
            xnA.y = fmaf(mc0A.y, k0, fmaf(mc1A.y, k1, cA.y));
            xnA.z = fmaf(mc0A.z, k0, fmaf(mc1A.z, k1, cA.z));
            xnA.w = fmaf(mc0A.w, k0, fmaf(mc1A.w, k1, cA.w));
            xnB.x = fmaf(mc0B.x, k0, fmaf(mc1B.x, k1, cB.x));
            xnB.y = fmaf(mc0B.y, k0, fmaf(mc1B.y, k1, cB.y));
            xnB.z = fmaf(mc0B.z, k0, fmaf(mc1B.z, k1, cB.z));
            xnB.w = fmaf(mc0B.w, k0, fmaf(mc1B.w, k1, cB.w));

            // FIX: per-lane offsets hA/hB were missing here in R2
            *reinterpret_cast<float4*>(trj + (size_t)t * HID + hA) = xnA;
            *reinterpret_cast<float4*>(trj + (size_t)t * HID + hB) = xnB;

            // r = tanh(x_new + bias); next kappa (critical path)
            float4 rA, rB;
            rA.x = tanh_from_arg(fmaf(CEXP, xnA.x, cbA.x));
            rA.y = tanh_from_arg(fmaf(CEXP, xnA.y, cbA.y));
            rA.z = tanh_from_arg(fmaf(CEXP, xnA.z, cbA.z));
            rA.w = tanh_from_arg(fmaf(CEXP, xnA.w, cbA.w));
            rB.x = tanh_from_arg(fmaf(CEXP, xnB.x, cbB.x));
            rB.y = tanh_from_arg(fmaf(CEXP, xnB.y, cbB.y));
            rB.z = tanh_from_arg(fmaf(CEXP, xnB.z, cbB.z));
            rB.w = tanh_from_arg(fmaf(CEXP, xnB.w, cbB.w));

            float p0 = dot44(rA, nc0A, rB, nc0B);
            float p1 = dot44(rA, nc1A, rB, nc1B);
            p0 = dpp_sum64(p0);
            p1 = dpp_sum64(p1);
            k0 = __builtin_bit_cast(float, __builtin_amdgcn_readlane(__builtin_bit_cast(int, p0), 63));
            k1 = __builtin_bit_cast(float, __builtin_amdgcn_readlane(__builtin_bit_cast(int, p1), 63));

            xA = xnA; xB = xnB;
        }
    }

    *reinterpret_cast<float4*>(out_xf + (size_t)b * HID + hA) = xA;
    *reinterpret_cast<float4*>(out_xf + (size_t)b * HID + hB) = xB;
}

// Kernel B: y[b,t,o] = sum_h tanh(traj[b,t+1,h]) * Wout[o,h]; wave-per-row.
__global__ __launch_bounds__(256, 4) void proj_kernel(
    const float* __restrict__ traj,   // [B,T+1,HID]
    const float* __restrict__ Wout,   // [OUT,HID]
    float* __restrict__ y)            // [B,T,OUT]
{
    const int lane = threadIdx.x & 63;
    const int gw   = (int)((blockIdx.x * blockDim.x + threadIdx.x) >> 6);
    const int nw   = (int)((gridDim.x * blockDim.x) >> 6);

    const float4 wa0 = *reinterpret_cast<const float4*>(Wout + 0 * HID + lane * 8);
    const float4 wa1 = *reinterpret_cast<const float4*>(Wout + 0 * HID + lane * 8 + 4);
    const float4 wb0 = *reinterpret_cast<const float4*>(Wout + 1 * HID + lane * 8);
    const float4 wb1 = *reinterpret_cast<const float4*>(Wout + 1 * HID + lane * 8 + 4);
    const float4 wc0 = *reinterpret_cast<const float4*>(Wout + 2 * HID + lane * 8);
    const float4 wc1 = *reinterpret_cast<const float4*>(Wout + 2 * HID + lane * 8 + 4);

    for (int row = gw; row < BB * TT; row += nw) {
        const int b = row / TT;
        const int t = row - b * TT;
        const float* src = traj + ((size_t)b * (TT + 1) + (t + 1)) * HID + lane * 8;
        const float4 a = *reinterpret_cast<const float4*>(src);
        const float4 c = *reinterpret_cast<const float4*>(src + 4);

        const float t0 = fast_tanh(a.x), t1 = fast_tanh(a.y);
        const float t2 = fast_tanh(a.z), t3 = fast_tanh(a.w);
        const float t4 = fast_tanh(c.x), t5 = fast_tanh(c.y);
        const float t6 = fast_tanh(c.z), t7 = fast_tanh(c.w);

        float y0 = t0*wa0.x + t1*wa0.y + t2*wa0.z + t3*wa0.w
                 + t4*wa1.x + t5*wa1.y + t6*wa1.z + t7*wa1.w;
        float y1 = t0*wb0.x + t1*wb0.y + t2*wb0.z + t3*wb0.w
                 + t4*wb1.x + t5*wb1.y + t6*wb1.z + t7*wb1.w;
        float y2 = t0*wc0.x + t1*wc0.y + t2*wc0.z + t3*wc0.w
                 + t4*wc1.x + t5*wc1.y + t6*wc1.z + t7*wc1.w;

        y0 = dpp_sum64(y0);
        y1 = dpp_sum64(y1);
        y2 = dpp_sum64(y2);

        if (lane == 63) {
            float* dst = y + (size_t)row * OUT;
            dst[0] = y0; dst[1] = y1; dst[2] = y2;
        }
    }
}

extern "C" void kernel_launch(void* const* d_in, const int* in_sizes, int n_in,
                              void* d_out, int out_size, void* d_ws, size_t ws_size,
                              hipStream_t stream) {
    const float* u     = (const float*)d_in[0];
    const float* x0    = (const float*)d_in[1];
    const float* noise = (const float*)d_in[2];
    const float* M     = (const float*)d_in[3];
    const float* Nw    = (const float*)d_in[4];
    const float* bias  = (const float*)d_in[5];
    const float* Win   = (const float*)d_in[6];
    const float* Wout  = (const float*)d_in[7];

    float* out_y  = (float*)d_out;                        // [B,T,OUT]
    float* out_xf = out_y + (size_t)BB * TT * OUT;        // [B,HID]
    float* traj   = out_xf + (size_t)BB * HID;            // [B,T+1,HID]

    rnn_scan_kernel<<<BB, 64, 0, stream>>>(u, x0, noise, M, Nw, bias, Win, out_xf, traj);
    proj_kernel<<<2048, 256, 0, stream>>>(traj, Wout, out_y);
}